// Round 10
// baseline (203.377 us; speedup 1.0000x reference)
//
#include <hip/hip_runtime.h>
#include <math.h>

#define C 256
#define S 4096
#define NH 8
#define NSG 16        // ksweep2 s-groups per bn (256 s each) = Mp partial groups
#define NSTRIP 32     // 128-s strips per bn = LP/ZP granularity
#define EPS 1e-5f
#define SCALE 0.17677669529663687f   // 1/sqrt(32)

#define PTS 272       // ptT LDS row stride (ushorts)

// workspace layout (float offsets)
#define OFF_GW  0                  // 64*256*8 = 131072 ([bn][c][h])
#define OFF_G   131072             // 512
#define OFF_BC  131584             // 512
#define OFF_PTT 132096             // 64*8*4096 ushorts = 1048576 floats
#define OFF_LP  1180672            // 512*32 = 16384
#define OFF_ZP  1197056            // 16384
#define OFF_IL  1213440            // 512
#define OFF_Z   1213952            // 512
#define OFF_MP  1214464            // 16*64*256*8 = 2097152
#define OFF_WEI 3311616            // 131072

typedef __attribute__((ext_vector_type(8))) short short8;
typedef __attribute__((ext_vector_type(4))) float f32x4;

__device__ __forceinline__ unsigned int bf_pack(float a, float b) {
    unsigned int ua = (__builtin_bit_cast(unsigned int, a) + 0x8000u) >> 16;
    unsigned int ub = (__builtin_bit_cast(unsigned int, b) + 0x8000u) & 0xffff0000u;
    return ua | ub;
}

// ---------------------------------------------------------------------------
// K1: LN(mask_tokens) -> q -> fold q into Wk. gw stored TRANSPOSED [c][h].
// ---------------------------------------------------------------------------
__global__ __launch_bounds__(256) void k1_prep(
    const float* __restrict__ mt, const float* __restrict__ ln_t_w, const float* __restrict__ ln_t_b,
    const float* __restrict__ ln_p_w, const float* __restrict__ ln_p_b,
    const float* __restrict__ Wq, const float* __restrict__ bq,
    const float* __restrict__ Wk, const float* __restrict__ bk,
    float* __restrict__ gw, float* __restrict__ Gv, float* __restrict__ Bc)
{
    int bn  = blockIdx.x;
    int tid = threadIdx.x;
    int wid = tid >> 6, lane = tid & 63;
    __shared__ float nt[C];
    __shared__ float qv[C];
    __shared__ float wks[NH][C];
    __shared__ float red[8];

    float x  = mt[bn * C + tid];
    float s1 = x, s2 = x * x;
    #pragma unroll
    for (int off = 32; off; off >>= 1) {
        s1 += __shfl_xor(s1, off);
        s2 += __shfl_xor(s2, off);
    }
    if (lane == 0) { red[wid] = s1; red[4 + wid] = s2; }
    __syncthreads();
    float mu   = (red[0] + red[1] + red[2] + red[3]) * (1.0f / C);
    float msq  = (red[4] + red[5] + red[6] + red[7]) * (1.0f / C);
    float rstd = rsqrtf(msq - mu * mu + EPS);
    nt[tid] = (x - mu) * rstd * ln_t_w[tid] + ln_t_b[tid];
    __syncthreads();

    {   // q[j=tid] = nt . Wq[j,:] + bq[j]
        float acc = bq[tid];
        const float* wrow = Wq + (size_t)tid * C;
        #pragma unroll 8
        for (int c = 0; c < C; ++c) acc += nt[c] * wrow[c];
        qv[tid] = acc;
    }
    __syncthreads();

    int c = tid;
    #pragma unroll
    for (int h = 0; h < NH; ++h) {
        float a = 0.f;
        #pragma unroll 4
        for (int d = 0; d < 32; ++d) a += qv[h * 32 + d] * Wk[(size_t)(h * 32 + d) * C + c];
        wks[h][c] = a * SCALE;
    }
    __syncthreads();

    for (int i = tid; i < C * NH; i += 256) {
        int cc = i >> 3, h = i & 7;
        gw[(size_t)bn * C * NH + i] = ln_p_w[cc] * wks[h][cc];
    }

    {
        int h = tid >> 5, l32 = tid & 31;
        float g = 0.f, bs = 0.f;
        #pragma unroll
        for (int cc = l32; cc < C; cc += 32) {
            float w = wks[h][cc];
            g  += ln_p_w[cc] * w;
            bs += ln_p_b[cc] * w;
        }
        float qb = qv[h * 32 + l32] * bk[h * 32 + l32];
        #pragma unroll
        for (int off = 16; off; off >>= 1) {
            g  += __shfl_xor(g, off);
            bs += __shfl_xor(bs, off);
            qb += __shfl_xor(qb, off);
        }
        if (l32 == 0) {
            Gv[bn * NH + h] = g;
            Bc[bn * NH + h] = bs + qb * SCALE;
        }
    }
}

// ---------------------------------------------------------------------------
// KSWEEP1: barrier-free score pass. Block = (bn, 512-s group), 4 waves.
// Wave owns 128 s x all 256 c. Lanes 0-31: even c, lanes 32-63: odd c
// (two 512B coalesced segments per load instr). g from 8KB LDS tile
// (2 broadcast b128/j). Per-s stats complete after ONE shfl_xor(32).
// Writes pt TRANSPOSED [bn][h][s] bf16 + per-wave LP/ZP. m=0 softmax.
// ---------------------------------------------------------------------------
__global__ __launch_bounds__(256) void ksweep1(
    const float* __restrict__ pe, const float* __restrict__ gw,
    const float* __restrict__ Gv, const float* __restrict__ Bc,
    unsigned short* __restrict__ ptg, float* __restrict__ LP, float* __restrict__ ZP)
{
    int blk = blockIdx.x;                    // 512
    int swz = (blk & 7) * 64 + (blk >> 3);   // XCD-contiguous chunks
    int bn  = swz >> 3;
    int sgrp= swz & 7;
    int tid = threadIdx.x;
    int w = tid >> 6, lane = tid & 63, l32 = lane & 31, hi = lane >> 5;
    int b = bn >> 3, n = bn & 7;
    const float* xb = pe + ((size_t)(n * 8 + b)) * C * S;

    __shared__ float gwt[C * NH];   // 8 KB
    {
        const float4* src = reinterpret_cast<const float4*>(gw + (size_t)bn * C * NH);
        float4* dst = reinterpret_cast<float4*>(gwt);
        for (int i = tid; i < C * NH / 4; i += 256) dst[i] = src[i];
    }
    __syncthreads();

    int s0 = sgrp * 512 + w * 128;           // wave s-base
    const float* xq = xb + s0 + l32 * 4;     // lane's 4 s

    float sum[4] = {0.f,0.f,0.f,0.f}, sq[4] = {0.f,0.f,0.f,0.f};
    float A[4][NH];
    #pragma unroll
    for (int e = 0; e < 4; ++e)
        #pragma unroll
        for (int h = 0; h < NH; ++h) A[e][h] = 0.f;

    #pragma unroll 8
    for (int j = 0; j < 128; ++j) {
        int cc = 2 * j + hi;
        float4 xv = *reinterpret_cast<const float4*>(xq + (size_t)cc * S);
        float4 g0 = *reinterpret_cast<const float4*>(&gwt[cc * 8]);
        float4 g1 = *reinterpret_cast<const float4*>(&gwt[cc * 8 + 4]);
        float xe[4] = {xv.x, xv.y, xv.z, xv.w};
        #pragma unroll
        for (int e = 0; e < 4; ++e) {
            float xx = xe[e];
            sum[e] += xx;
            sq[e]  += xx * xx;
            A[e][0] += g0.x * xx; A[e][1] += g0.y * xx;
            A[e][2] += g0.z * xx; A[e][3] += g0.w * xx;
            A[e][4] += g1.x * xx; A[e][5] += g1.y * xx;
            A[e][6] += g1.z * xx; A[e][7] += g1.w * xx;
        }
    }
    // parity combine: lane pair (l, l^32) holds even/odd c halves of SAME s
    #pragma unroll
    for (int e = 0; e < 4; ++e) {
        sum[e] += __shfl_xor(sum[e], 32);
        sq[e]  += __shfl_xor(sq[e],  32);
        #pragma unroll
        for (int h = 0; h < NH; ++h) A[e][h] += __shfl_xor(A[e][h], 32);
    }

    float Gh[NH], Bh[NH];
    #pragma unroll
    for (int h = 0; h < NH; ++h) { Gh[h] = Gv[bn * NH + h]; Bh[h] = Bc[bn * NH + h]; }

    float lp[NH], zp[NH], pt[4][NH];
    #pragma unroll
    for (int h = 0; h < NH; ++h) { lp[h] = 0.f; zp[h] = 0.f; }
    #pragma unroll
    for (int e = 0; e < 4; ++e) {
        float mu   = sum[e] * (1.f / C);
        float var  = sq[e] * (1.f / C) - mu * mu;
        float rs   = rsqrtf(var + EPS);
        float murv = mu * rs;
        #pragma unroll
        for (int h = 0; h < NH; ++h) {
            float p = __expf(rs * A[e][h] - murv * Gh[h] + Bh[h]);  // m=0 (validated r4-r9)
            pt[e][h] = p * rs;
            lp[h] += p;
            zp[h] += p * murv;
        }
    }

    // store pt transposed [bn][h][s] bf16; lanes 0-31 only (pair duplicates)
    if (hi == 0) {
        #pragma unroll
        for (int h = 0; h < NH; ++h) {
            uint2 pk;
            pk.x = bf_pack(pt[0][h], pt[1][h]);
            pk.y = bf_pack(pt[2][h], pt[3][h]);
            *reinterpret_cast<uint2*>(ptg + ((size_t)(bn * NH + h)) * S + s0 + l32 * 4) = pk;
        }
    }

    // LP/ZP: reduce lanes 0-31 (each s counted once)
    #pragma unroll
    for (int h = 0; h < NH; ++h) {
        float l = lp[h], zz = zp[h];
        #pragma unroll
        for (int off = 16; off; off >>= 1) {
            l  += __shfl_xor(l,  off);
            zz += __shfl_xor(zz, off);
        }
        if (lane == 0) {
            int strip = sgrp * 4 + w;
            LP[(size_t)(bn * NH + h) * NSTRIP + strip] = l;
            ZP[(size_t)(bn * NH + h) * NSTRIP + strip] = zz;
        }
    }
}

// ---------------------------------------------------------------------------
// KSWEEP2: MFMA PV pass. Block = (bn, 256-s group), 4 waves. ptT staged from
// global to LDS (coalesced); A from x (L3-resident after ksweep1);
// M[c][h] = sum_s x[c,s]*pt[s,h] via mfma_f32_16x16x32_bf16. D -> LDS -> Mp.
// ---------------------------------------------------------------------------
__global__ __launch_bounds__(256) void ksweep2(
    const float* __restrict__ pe, const unsigned short* __restrict__ ptg,
    float* __restrict__ Mp)
{
    int blk = blockIdx.x;                     // 1024
    int swz = (blk & 7) * 128 + (blk >> 3);
    int bn  = swz >> 4;
    int sg  = swz & 15;
    int tid = threadIdx.x;
    int w   = tid >> 6, lane = tid & 63;
    int b = bn >> 3, n = bn & 7;
    const float* xb = pe + ((size_t)(n * 8 + b)) * C * S;
    int sgbase = sg * 256;

    __shared__ unsigned short ptT[16 * PTS];   // 8704 B
    __shared__ float Dstage[C * NH];           // 8192 B

    // stage ptT rows 0-7 from global (uint = 2 ushorts, coalesced), rows 8-15 zero
    for (int i = tid; i < 16 * 128; i += 256) {
        int h = i >> 7, si = (i & 127) * 2;
        unsigned int v = 0;
        if (h < NH)
            v = *reinterpret_cast<const unsigned int*>(
                    ptg + ((size_t)(bn * NH + h)) * S + sgbase + si);
        *reinterpret_cast<unsigned int*>(&ptT[h * PTS + si]) = v;
    }
    __syncthreads();

    {
        int mrow = lane & 15;     // A row within tile; D col (= h)
        int kgrp = lane >> 4;     // k block (8 k each)
        #pragma unroll
        for (int ct = 0; ct < 4; ++ct) {
            int ctile = w * 4 + ct;
            int crow  = ctile * 16 + mrow;
            const float* arow = xb + (size_t)crow * S + sgbase + kgrp * 8;
            f32x4 acc = {0.f, 0.f, 0.f, 0.f};
            #pragma unroll
            for (int kc = 0; kc < 8; ++kc) {
                float4 a0 = *reinterpret_cast<const float4*>(arow + kc * 32);
                float4 a1 = *reinterpret_cast<const float4*>(arow + kc * 32 + 4);
                uint4 ap;
                ap.x = bf_pack(a0.x, a0.y);
                ap.y = bf_pack(a0.z, a0.w);
                ap.z = bf_pack(a1.x, a1.y);
                ap.w = bf_pack(a1.z, a1.w);
                short8 af = __builtin_bit_cast(short8, ap);
                uint4 bp = *reinterpret_cast<const uint4*>(&ptT[mrow * PTS + kc * 32 + kgrp * 8]);
                short8 bfv = __builtin_bit_cast(short8, bp);
                acc = __builtin_amdgcn_mfma_f32_16x16x32_bf16(af, bfv, acc, 0, 0, 0);
            }
            if (mrow < NH) {
                #pragma unroll
                for (int r = 0; r < 4; ++r) {
                    int cl = ctile * 16 + kgrp * 4 + r;
                    Dstage[cl * NH + mrow] = acc[r];
                }
            }
        }
    }
    __syncthreads();

    // coalesced Mp write (2048 floats)
    {
        float* mp = Mp + (((size_t)sg * 64 + bn) * C) * NH;
        #pragma unroll
        for (int i = 0; i < 2; ++i) {
            int idx = tid * 8 + i * 4;
            *reinterpret_cast<float4*>(mp + idx) =
                *reinterpret_cast<const float4*>(&Dstage[idx]);
        }
    }
}

// ---------------------------------------------------------------------------
// K3 (tiny): L = sum of 32 strip partials, IL = 1/L, z = Z/L per (bn,h).
// ---------------------------------------------------------------------------
__global__ __launch_bounds__(64) void k3_combine(
    const float* __restrict__ LP, const float* __restrict__ ZP,
    float* __restrict__ IL, float* __restrict__ z)
{
    int idx = blockIdx.x * 64 + threadIdx.x;   // bn*8+h, 512 total
    const float4* lp4 = reinterpret_cast<const float4*>(LP + (size_t)idx * NSTRIP);
    const float4* zp4 = reinterpret_cast<const float4*>(ZP + (size_t)idx * NSTRIP);
    float L = 0.f, Zs = 0.f;
    #pragma unroll
    for (int j = 0; j < 8; ++j) {
        float4 a  = lp4[j];
        float4 cz = zp4[j];
        L  += a.x + a.y + a.z + a.w;
        Zs += cz.x + cz.y + cz.z + cz.w;
    }
    float inv = 1.f / L;
    IL[idx] = inv;
    z[idx]  = Zs * inv;
}

// ---------------------------------------------------------------------------
// KFOLD: fold 16 Mp partials, apply IL/z/ln_p -> wei[bn][h][c] global.
// ---------------------------------------------------------------------------
__global__ __launch_bounds__(256) void kfold(
    const float* __restrict__ Mp, const float* __restrict__ IL, const float* __restrict__ z,
    const float* __restrict__ lpw, const float* __restrict__ lpb, float* __restrict__ weig)
{
    int blk = blockIdx.x;
    int bn = blk >> 3, slice = blk & 7;
    int tid = threadIdx.x;
    int c = slice * 32 + (tid >> 3), h = tid & 7;
    float m = 0.f;
    #pragma unroll
    for (int sgi = 0; sgi < NSG; ++sgi)
        m += Mp[(((size_t)sgi * 64 + bn) * C + c) * NH + h];
    float Mn = m * IL[bn * NH + h];
    weig[(size_t)bn * NH * C + h * C + c] = lpw[c] * (Mn - z[bn * NH + h]) + lpb[c];
}

// ---------------------------------------------------------------------------
// K5: wei (global) -> ctx -> Wo -> residual -> MLP -> out. Per-thread serial-K
// GEMVs (L2-hot weight rows, ILP loads).
// ---------------------------------------------------------------------------
__global__ __launch_bounds__(256) void k5_out(
    const float* __restrict__ mt, const float* __restrict__ weig,
    const float* __restrict__ Wv, const float* __restrict__ bv,
    const float* __restrict__ Wo, const float* __restrict__ bo,
    const float* __restrict__ W1, const float* __restrict__ b1,
    const float* __restrict__ W2, const float* __restrict__ b2,
    float* __restrict__ out)
{
    int bn  = blockIdx.x;
    int tid = threadIdx.x;
    __shared__ float wei[NH * C];   // [h][c]
    __shared__ float ctxs[C];
    __shared__ float upds[C];
    __shared__ float hid[2 * C];

    for (int v = tid; v < 512; v += 256)
        *reinterpret_cast<float4*>(&wei[v * 4]) =
            *reinterpret_cast<const float4*>(weig + (size_t)bn * NH * C + v * 4);
    __syncthreads();

    {   // ctx[j=tid] = wei[h(j),:] . Wv[j,:] + bv[j]
        int h = tid >> 5;
        float a = bv[tid];
        const float* wrow = Wv + (size_t)tid * C;
        const float* wh   = wei + h * C;
        #pragma unroll 8
        for (int c2 = 0; c2 < C; ++c2) a += wh[c2] * wrow[c2];
        ctxs[tid] = a;
    }
    __syncthreads();

    float att = bo[tid];
    {
        const float* wrow = Wo + (size_t)tid * C;
        #pragma unroll 8
        for (int j = 0; j < C; ++j) att += ctxs[j] * wrow[j];
    }
    float upd = mt[(size_t)bn * C + tid] + att;
    upds[tid] = upd;
    __syncthreads();

    #pragma unroll
    for (int r = 0; r < 2; ++r) {
        int k = tid + r * 256;
        float a = b1[k];
        const float* wrow = W1 + (size_t)k * C;
        #pragma unroll 8
        for (int c2 = 0; c2 < C; ++c2) a += upds[c2] * wrow[c2];
        hid[k] = fmaxf(a, 0.f);
    }
    __syncthreads();

    float a = b2[tid];
    const float* wrow = W2 + (size_t)tid * 2 * C;
    #pragma unroll 8
    for (int k = 0; k < 2 * C; ++k) a += hid[k] * wrow[k];
    out[(size_t)bn * C + tid] = upd + a;
}

extern "C" void kernel_launch(void* const* d_in, const int* in_sizes, int n_in,
                              void* d_out, int out_size, void* d_ws, size_t ws_size,
                              hipStream_t stream)
{
    const float* mt  = (const float*)d_in[0];
    const float* pe  = (const float*)d_in[1];
    const float* ltw = (const float*)d_in[2];
    const float* ltb = (const float*)d_in[3];
    const float* lpw = (const float*)d_in[4];
    const float* lpb = (const float*)d_in[5];
    const float* Wq  = (const float*)d_in[6];
    const float* bq  = (const float*)d_in[7];
    const float* Wk  = (const float*)d_in[8];
    const float* bk  = (const float*)d_in[9];
    const float* Wv  = (const float*)d_in[10];
    const float* bv  = (const float*)d_in[11];
    const float* Wo  = (const float*)d_in[12];
    const float* bo  = (const float*)d_in[13];
    const float* W1  = (const float*)d_in[14];
    const float* b1  = (const float*)d_in[15];
    const float* W2  = (const float*)d_in[16];
    const float* b2  = (const float*)d_in[17];

    float* ws   = (float*)d_ws;
    float* outp = (float*)d_out;

    float* gw            = ws + OFF_GW;
    float* Gv            = ws + OFF_G;
    float* Bc            = ws + OFF_BC;
    unsigned short* ptg  = (unsigned short*)(ws + OFF_PTT);
    float* LP            = ws + OFF_LP;
    float* ZP            = ws + OFF_ZP;
    float* ILv           = ws + OFF_IL;
    float* z             = ws + OFF_Z;
    float* Mp            = ws + OFF_MP;
    float* weig          = ws + OFF_WEI;

    k1_prep   <<<64,   256, 0, stream>>>(mt, ltw, ltb, lpw, lpb, Wq, bq, Wk, bk, gw, Gv, Bc);
    ksweep1   <<<512,  256, 0, stream>>>(pe, gw, Gv, Bc, ptg, LP, ZP);
    ksweep2   <<<1024, 256, 0, stream>>>(pe, ptg, Mp);
    k3_combine<<<8,    64,  0, stream>>>(LP, ZP, ILv, z);
    kfold     <<<512,  256, 0, stream>>>(Mp, ILv, z, lpw, lpb, weig);
    k5_out    <<<64,   256, 0, stream>>>(mt, weig, Wv, bv, Wo, bo, W1, b1, W2, b2, outp);
}